// Round 19
// baseline (105.199 us; speedup 1.0000x reference)
//
#include <hip/hip_runtime.h>

typedef unsigned int u32;
typedef unsigned short u16;
typedef __attribute__((ext_vector_type(8))) short bf16x8;
typedef __attribute__((ext_vector_type(4))) float f32x4;

#define T_ 2048
#define HEADS 16
#define DH 64

__device__ __forceinline__ u16 f2bf(float f) {
    union { float f; u32 u; } x; x.f = f;
    return (u16)((x.u + 0x7fffu + ((x.u >> 16) & 1u)) >> 16);
}
// packed f32x2 -> bf16x2 (RNE), single HW instruction
__device__ __forceinline__ u32 pkbf(float lo, float hi) {
    u32 r;
    asm("v_cvt_pk_bf16_f32 %0, %1, %2" : "=v"(r) : "v"(lo), "v"(hi));
    return r;
}
// async global->LDS, 16B per lane: LDS dest = wave-uniform base + lane*16
__device__ __forceinline__ void gll16(const void* g, void* l) {
    __builtin_amdgcn_global_load_lds(
        (const __attribute__((address_space(1))) void*)g,
        (__attribute__((address_space(3))) void*)l, 16, 0, 0);
}

// q pre-scaled by 1/sqrt(64) * log2(e) so softmax runs in exp2 domain
#define QSCALE 0.18033688011112042f
#define DEFER_THR 8.0f

// ============ fused fp32 [rows][1024] -> bf16 tile-major pre-swizzled (3 tensors) ============
#define NG_X  (4096 * 128)
#define NG_WA (3072 * 128)
__global__ __launch_bounds__(256) void cvt_all(
    const float* __restrict__ x, const float* __restrict__ wa,
    const float* __restrict__ wp,
    u16* __restrict__ dx, u16* __restrict__ dwa, u16* __restrict__ dwp)
{
    int gid = blockIdx.x * 256 + threadIdx.x;
    const float* src; u16* dst;
    if (gid < NG_X)                { src = x;  dst = dx; }
    else if (gid < NG_X + NG_WA)   { src = wa; dst = dwa; gid -= NG_X; }
    else                           { src = wp; dst = dwp; gid -= NG_X + NG_WA; }
    const int m = gid >> 7, s = gid & 127;
    const int kt = s >> 3, seg = s & 7;
    const float4 a0 = *(const float4*)&src[m * 1024 + s * 8];
    const float4 a1 = *(const float4*)&src[m * 1024 + s * 8 + 4];
    uint4 t;
    t.x = pkbf(a0.x, a0.y); t.y = pkbf(a0.z, a0.w);
    t.z = pkbf(a1.x, a1.y); t.w = pkbf(a1.z, a1.w);
    const int mt = m >> 7, r = m & 127;
    char* d = (char*)dst + ((size_t)(mt * 16 + kt)) * 16384
              + r * 128 + ((seg ^ (r & 7)) << 4);
    *(uint4*)d = t;
}

// ================= MFMA GEMM via global_load_lds (m97 single-buffer, R15 winner) =================
template<int EPI>
__global__ __launch_bounds__(256, 3) void gemm_lds(
    const char* __restrict__ At, const char* __restrict__ Bt,
    const float* __restrict__ bias,
    u16* __restrict__ q, u16* __restrict__ k, u16* __restrict__ vt,
    float* __restrict__ outF)
{
    __shared__ __align__(16) char AsB[16384];
    __shared__ __align__(16) char BsB[16384];
    const int tid = threadIdx.x;
    const int l = tid & 63, li = l & 15, lg = l >> 4;
    const int w = tid >> 6, wm = w >> 1, wn = w & 1;
    const int m0 = blockIdx.y * 128, n0 = blockIdx.x * 128;
    const char* Ab = At + (size_t)blockIdx.y * (16 * 16384);
    const char* Bb = Bt + (size_t)blockIdx.x * (16 * 16384);

    f32x4 acc[4][4];
    #pragma unroll
    for (int i = 0; i < 4; ++i)
        #pragma unroll
        for (int j = 0; j < 4; ++j) acc[i][j] = (f32x4){0.f, 0.f, 0.f, 0.f};

    for (int kt = 0; kt < 16; ++kt) {
        const char* An = Ab + kt * 16384;
        const char* Bn = Bb + kt * 16384;
        #pragma unroll
        for (int i = 0; i < 4; ++i) {
            gll16(An + w * 4096 + i * 1024 + l * 16, &AsB[w * 4096 + i * 1024]);
            gll16(Bn + w * 4096 + i * 1024 + l * 16, &BsB[w * 4096 + i * 1024]);
        }
        asm volatile("s_waitcnt vmcnt(0)" ::: "memory");
        __syncthreads();
        #pragma unroll
        for (int kc = 0; kc < 2; ++kc) {
            const int key = ((kc * 4 + lg) ^ (li & 7)) << 4;
            bf16x8 a[4], b[4];
            #pragma unroll
            for (int f = 0; f < 4; ++f)
                a[f] = *(const bf16x8*)&AsB[(wm * 64 + f * 16 + li) * 128 + key];
            #pragma unroll
            for (int f = 0; f < 4; ++f)
                b[f] = *(const bf16x8*)&BsB[(wn * 64 + f * 16 + li) * 128 + key];
            #pragma unroll
            for (int mi = 0; mi < 4; ++mi)
                #pragma unroll
                for (int ni = 0; ni < 4; ++ni)
                    acc[mi][ni] = __builtin_amdgcn_mfma_f32_16x16x32_bf16(a[mi], b[ni], acc[mi][ni], 0, 0, 0);
        }
        __syncthreads();
    }

    const int mb = m0 + wm * 64;
    const int nb0 = n0 + wn * 64;
    if constexpr (EPI == 0) {
        const int part = n0 >> 10;
        if (part < 2) {
            u16* dst = (part == 0) ? q : k;
            const float scl = (part == 0) ? QSCALE : 1.0f;
            #pragma unroll
            for (int mi = 0; mi < 4; ++mi)
                #pragma unroll
                for (int r = 0; r < 4; ++r) {
                    const int m = mb + mi * 16 + lg * 4 + r;
                    const int bb = m >> 11, t = m & 2047;
                    #pragma unroll
                    for (int ni = 0; ni < 4; ++ni) {
                        const int n = nb0 + ni * 16 + li;
                        const int c = n & 1023;
                        const int h = c >> 6, d = c & 63;
                        const float val = (acc[mi][ni][r] + bias[n]) * scl;
                        dst[(((bb << 4) + h) * T_ + t) * DH + d] = f2bf(val);
                    }
                }
        } else {
            // V transposed: vt[((b*16+h)*64 + d)*2048 + t]
            #pragma unroll
            for (int mi = 0; mi < 4; ++mi) {
                const int m = mb + mi * 16 + lg * 4;
                const int bb = m >> 11, t0 = m & 2047;
                #pragma unroll
                for (int ni = 0; ni < 4; ++ni) {
                    const int n = nb0 + ni * 16 + li;
                    const int c = n & 1023;
                    const int h = c >> 6, d = c & 63;
                    const float bz = bias[n];
                    u32 w0 = pkbf(acc[mi][ni][0] + bz, acc[mi][ni][1] + bz);
                    u32 w1 = pkbf(acc[mi][ni][2] + bz, acc[mi][ni][3] + bz);
                    *(uint2*)&vt[(((bb << 4) + h) * 64 + d) * (size_t)T_ + t0] = make_uint2(w0, w1);
                }
            }
        }
    } else {
        #pragma unroll
        for (int mi = 0; mi < 4; ++mi)
            #pragma unroll
            for (int r = 0; r < 4; ++r) {
                const int m = mb + mi * 16 + lg * 4 + r;
                #pragma unroll
                for (int ni = 0; ni < 4; ++ni) {
                    const int n = nb0 + ni * 16 + li;
                    outF[m * 1024 + n] = acc[mi][ni][r] + bias[n];
                }
            }
    }
}

// ---------------- MFMA flash attention v12-LPT-SB: single-buffer K/V, 6 blocks/CU ----------------
// Exact v12 wave-level compute (best measured). Changes vs R18 winner:
//   - K/V single-buffered (LDS 40KB -> 24KB -> 6 blocks/CU; launch_bounds(256,4))
//   - 2 barriers/tile: reads-done fence, then LDS rewrite, then visibility fence.
//   - LPT slot map retained (qt = 31 - slot).
// Reg-prefetch of the next tile still hides global latency; cross-block overlap (m114)
// hides the extra barrier.
__global__ __launch_bounds__(256, 4) void flash_attn(
    const u16* __restrict__ Q, const u16* __restrict__ K,
    const u16* __restrict__ Vt, char* __restrict__ Yt)
{
    __shared__ __align__(16) char KsB[8192];
    __shared__ __align__(16) char VsB[8192];
    __shared__ __align__(16) char PsB[4][2048];

    const int bh = blockIdx.x;
    const int slot = blockIdx.y;
    const int qt = 31 - slot;                     // LPT: heaviest first
    const int tid = threadIdx.x;
    const int w  = tid >> 6;
    const int l  = tid & 63;
    const int li = l & 15, lg = l >> 4;
    const u16* Qb = Q  + (size_t)bh * (T_ * DH);
    const u16* Kb = K  + (size_t)bh * (T_ * DH);
    const u16* Vb = Vt + (size_t)bh * (T_ * DH);   // rows (d) of length T_
    const int srow = tid >> 3;   // 0..31
    const int sseg = tid & 7;    // 16B segment
    char* Pw = PsB[w];
    const int b = bh >> 4, h = bh & 15;
    const int skey = (srow & 7) << 4;   // (srow+32)&7 == srow&7
    const int rdkey = (li & 7) << 4;

    const int wq0 = qt * 64 + w * 16;
    const int q_row = wq0 + li;          // this lane's q row
    const int nkv = qt + 1;

    bf16x8 qa[2];
    qa[0] = *(const bf16x8*)(Qb + q_row * 64 + 0  + lg * 8);
    qa[1] = *(const bf16x8*)(Qb + q_row * 64 + 32 + lg * 8);

    f32x4 o[4];   // o[nb][r] = O[q=li][d=nb*16+lg*4+r]
    #pragma unroll
    for (int nb = 0; nb < 4; ++nb) o[nb] = (f32x4){0.f, 0.f, 0.f, 0.f};
    float m_r = -INFINITY, l_r = 0.f;    // lane-scalar (q-row li)

    uint4 kr0, kr1, vr0, vr1;
    // ---- prologue: stage tile 0 (rows srow and srow+32) ----
    kr0 = *(const uint4*)(Kb + srow * 64 + sseg * 8);
    kr1 = *(const uint4*)(Kb + (srow + 32) * 64 + sseg * 8);
    vr0 = *(const uint4*)(Vb + (size_t)srow * T_ + sseg * 8);
    vr1 = *(const uint4*)(Vb + (size_t)(srow + 32) * T_ + sseg * 8);
    *(uint4*)&KsB[srow * 128        + ((sseg << 4) ^ skey)] = kr0;
    *(uint4*)&KsB[(srow + 32) * 128 + ((sseg << 4) ^ skey)] = kr1;
    *(uint4*)&VsB[srow * 128        + ((sseg << 4) ^ skey)] = vr0;
    *(uint4*)&VsB[(srow + 32) * 128 + ((sseg << 4) ^ skey)] = vr1;
    __syncthreads();

    for (int j = 0; j < nkv; ++j) {
        const bool has_next = (j + 1 < nkv);
        // ---- issue next tile's global loads (latency hides under compute) ----
        if (has_next) {
            const int t0 = (j + 1) * 64;
            kr0 = *(const uint4*)(Kb + (t0 + srow) * 64 + sseg * 8);
            kr1 = *(const uint4*)(Kb + (t0 + srow + 32) * 64 + sseg * 8);
            vr0 = *(const uint4*)(Vb + (size_t)srow * T_ + t0 + sseg * 8);
            vr1 = *(const uint4*)(Vb + (size_t)(srow + 32) * T_ + t0 + sseg * 8);
        }
        // ---- S^T = K.Q^T : s[f][r] = S[q=li][k = j*64 + f*16 + lg*4 + r] ----
        f32x4 s[4];
        __builtin_amdgcn_s_setprio(1);
        #pragma unroll
        for (int f = 0; f < 4; ++f) {
            s[f] = (f32x4){0.f, 0.f, 0.f, 0.f};
            #pragma unroll
            for (int c = 0; c < 2; ++c) {
                bf16x8 kb = *(const bf16x8*)&KsB[(f * 16 + li) * 128 + ((c * 64 + lg * 16) ^ rdkey)];
                s[f] = __builtin_amdgcn_mfma_f32_16x16x32_bf16(kb, qa[c], s[f], 0, 0, 0);
            }
        }
        __builtin_amdgcn_s_setprio(0);
        // ---- causal mask on diagonal tile (only j==qt can cross) ----
        if ((j + 1) * 64 > wq0) {
            const int kbase = j * 64 + lg * 4;
            #pragma unroll
            for (int f = 0; f < 4; ++f)
                #pragma unroll
                for (int r = 0; r < 4; ++r)
                    if (kbase + f * 16 + r > q_row) s[f][r] = -INFINITY;
        }
        // ---- softmax: lane-local max check; cross-reduce only on rescale ----
        float lm = s[0][0];
        #pragma unroll
        for (int f = 0; f < 4; ++f)
            #pragma unroll
            for (int r = 0; r < 4; ++r) lm = fmaxf(lm, s[f][r]);
        if (!__all(lm <= m_r + DEFER_THR)) {
            float tm = lm;
            tm = fmaxf(tm, __shfl_xor(tm, 16));
            tm = fmaxf(tm, __shfl_xor(tm, 32));
            const float mnew = fmaxf(m_r, tm);
            const float corr = exp2f(m_r - mnew);
            m_r = mnew;
            l_r *= corr;
            #pragma unroll
            for (int nb = 0; nb < 4; ++nb)
                #pragma unroll
                for (int r = 0; r < 4; ++r) o[nb][r] *= corr;
        }
        // ---- P = exp2(S - m), accumulate l, pack & write (4x ds_write_b64) ----
        #pragma unroll
        for (int f = 0; f < 4; ++f) {
            float p0 = exp2f(s[f][0] - m_r);
            float p1 = exp2f(s[f][1] - m_r);
            float p2 = exp2f(s[f][2] - m_r);
            float p3 = exp2f(s[f][3] - m_r);
            l_r += (p0 + p1) + (p2 + p3);
            uint2 pk = make_uint2(pkbf(p0, p1), pkbf(p2, p3));
            *(uint2*)&Pw[li * 128 + (((f * 32 + lg * 8)) ^ rdkey)] = pk;
        }
        // ---- O^T += V^T.P^T : o[nb][r] = O[q=li][d=nb*16+lg*4+r] ----
        __builtin_amdgcn_s_setprio(1);
        #pragma unroll
        for (int c = 0; c < 2; ++c) {
            bf16x8 pa = *(const bf16x8*)&Pw[li * 128 + ((c * 64 + lg * 16) ^ rdkey)];
            #pragma unroll
            for (int nb = 0; nb < 4; ++nb) {
                bf16x8 vb = *(const bf16x8*)&VsB[(nb * 16 + li) * 128 + ((c * 64 + lg * 16) ^ rdkey)];
                o[nb] = __builtin_amdgcn_mfma_f32_16x16x32_bf16(vb, pa, o[nb], 0, 0, 0);
            }
        }
        __builtin_amdgcn_s_setprio(0);
        __syncthreads();               // all K/V reads of tile j complete
        if (has_next) {
            *(uint4*)&KsB[srow * 128        + ((sseg << 4) ^ skey)] = kr0;
            *(uint4*)&KsB[(srow + 32) * 128 + ((sseg << 4) ^ skey)] = kr1;
            *(uint4*)&VsB[srow * 128        + ((sseg << 4) ^ skey)] = vr0;
            *(uint4*)&VsB[(srow + 32) * 128 + ((sseg << 4) ^ skey)] = vr1;
        }
        __syncthreads();               // tile j+1 visible
    }

    // ---- epilogue: cross-reduce l, normalize, write Y (tiled-swizzled, 8B stores) ----
    l_r += __shfl_xor(l_r, 16);
    l_r += __shfl_xor(l_r, 32);
    const float inv = 1.0f / l_r;
    // matrix row = b*2048 + qt*64 + w*16 + li  ->  mt = b*16 + (qt>>1)
    const int r128 = (qt & 1) * 64 + w * 16 + li;
    const int rk = (r128 & 7) << 4;
    char* yrow = Yt + ((size_t)((b * 16 + (qt >> 1)) * 16 + h)) * 16384 + r128 * 128;
    #pragma unroll
    for (int nb = 0; nb < 4; ++nb) {
        // d = nb*16 + lg*4 + r, r=0..3 -> seg = 2nb + (lg>>1), byte e0 = (lg&1)*8
        const int seg = 2 * nb + (lg >> 1);
        uint2 pk = make_uint2(pkbf(o[nb][0] * inv, o[nb][1] * inv),
                              pkbf(o[nb][2] * inv, o[nb][3] * inv));
        *(uint2*)&yrow[((seg << 4) ^ rk) + (lg & 1) * 8] = pk;
    }
}

extern "C" void kernel_launch(void* const* d_in, const int* in_sizes, int n_in,
                              void* d_out, int out_size, void* d_ws, size_t ws_size,
                              hipStream_t stream) {
    const float* x      = (const float*)d_in[0];
    const float* W_attn = (const float*)d_in[1];
    const float* b_attn = (const float*)d_in[2];
    const float* W_proj = (const float*)d_in[3];
    const float* b_proj = (const float*)d_in[4];
    float* out = (float*)d_out;

    char* ws = (char*)d_ws;
    u16* q   = (u16*)ws;                          // [B,H,T,D] bf16, 8 MB
    u16* k   = (u16*)(ws + (8u << 20));           // [B,H,T,D] 8 MB
    u16* vt  = (u16*)(ws + (16u << 20));          // [B,H,D,T] 8 MB
    char* xb = ws + (24u << 20);                  // x tiled bf16 8 MB; REUSED as Yt after qkv
    char* wab = ws + (32u << 20);                 // W_attn tiled bf16 6 MB
    char* wpb = ws + (38u << 20);                 // W_proj tiled bf16 2 MB

    cvt_all<<<4096, 256, 0, stream>>>(x, W_attn, W_proj, (u16*)xb, (u16*)wab, (u16*)wpb);
    gemm_lds<0><<<dim3(24, 32), 256, 0, stream>>>(xb, wab, b_attn, q, k, vt, nullptr);
    flash_attn<<<dim3(32, 32), 256, 0, stream>>>(q, k, vt, xb /* Yt */);
    gemm_lds<1><<<dim3(8, 32), 256, 0, stream>>>(xb /* Yt */, wpb, b_proj,
                                                 nullptr, nullptr, nullptr, out);
}

// Round 20
// 104.484 us; speedup vs baseline: 1.0068x; 1.0068x over previous
//
#include <hip/hip_runtime.h>

typedef unsigned int u32;
typedef unsigned short u16;
typedef __attribute__((ext_vector_type(8))) short bf16x8;
typedef __attribute__((ext_vector_type(4))) float f32x4;

#define T_ 2048
#define HEADS 16
#define DH 64

__device__ __forceinline__ u16 f2bf(float f) {
    union { float f; u32 u; } x; x.f = f;
    return (u16)((x.u + 0x7fffu + ((x.u >> 16) & 1u)) >> 16);
}
// packed f32x2 -> bf16x2 (RNE), single HW instruction
__device__ __forceinline__ u32 pkbf(float lo, float hi) {
    u32 r;
    asm("v_cvt_pk_bf16_f32 %0, %1, %2" : "=v"(r) : "v"(lo), "v"(hi));
    return r;
}
// async global->LDS, 16B per lane: LDS dest = wave-uniform base + lane*16
__device__ __forceinline__ void gll16(const void* g, void* l) {
    __builtin_amdgcn_global_load_lds(
        (const __attribute__((address_space(1))) void*)g,
        (__attribute__((address_space(3))) void*)l, 16, 0, 0);
}

// q pre-scaled by 1/sqrt(64) * log2(e) so softmax runs in exp2 domain
#define QSCALE 0.18033688011112042f
#define DEFER_THR 8.0f

// ============ fused fp32 [rows][1024] -> bf16 tile-major pre-swizzled (3 tensors) ============
#define NG_X  (4096 * 128)
#define NG_WA (3072 * 128)
__global__ __launch_bounds__(256) void cvt_all(
    const float* __restrict__ x, const float* __restrict__ wa,
    const float* __restrict__ wp,
    u16* __restrict__ dx, u16* __restrict__ dwa, u16* __restrict__ dwp)
{
    int gid = blockIdx.x * 256 + threadIdx.x;
    const float* src; u16* dst;
    if (gid < NG_X)                { src = x;  dst = dx; }
    else if (gid < NG_X + NG_WA)   { src = wa; dst = dwa; gid -= NG_X; }
    else                           { src = wp; dst = dwp; gid -= NG_X + NG_WA; }
    const int m = gid >> 7, s = gid & 127;
    const int kt = s >> 3, seg = s & 7;
    const float4 a0 = *(const float4*)&src[m * 1024 + s * 8];
    const float4 a1 = *(const float4*)&src[m * 1024 + s * 8 + 4];
    uint4 t;
    t.x = pkbf(a0.x, a0.y); t.y = pkbf(a0.z, a0.w);
    t.z = pkbf(a1.x, a1.y); t.w = pkbf(a1.z, a1.w);
    const int mt = m >> 7, r = m & 127;
    char* d = (char*)dst + ((size_t)(mt * 16 + kt)) * 16384
              + r * 128 + ((seg ^ (r & 7)) << 4);
    *(uint4*)d = t;
}

// ================= MFMA GEMM via global_load_lds (m97 single-buffer, R15 winner) =================
template<int EPI>
__global__ __launch_bounds__(256, 3) void gemm_lds(
    const char* __restrict__ At, const char* __restrict__ Bt,
    const float* __restrict__ bias,
    u16* __restrict__ q, u16* __restrict__ k, u16* __restrict__ vt,
    float* __restrict__ outF)
{
    __shared__ __align__(16) char AsB[16384];
    __shared__ __align__(16) char BsB[16384];
    const int tid = threadIdx.x;
    const int l = tid & 63, li = l & 15, lg = l >> 4;
    const int w = tid >> 6, wm = w >> 1, wn = w & 1;
    const int m0 = blockIdx.y * 128, n0 = blockIdx.x * 128;
    const char* Ab = At + (size_t)blockIdx.y * (16 * 16384);
    const char* Bb = Bt + (size_t)blockIdx.x * (16 * 16384);

    f32x4 acc[4][4];
    #pragma unroll
    for (int i = 0; i < 4; ++i)
        #pragma unroll
        for (int j = 0; j < 4; ++j) acc[i][j] = (f32x4){0.f, 0.f, 0.f, 0.f};

    for (int kt = 0; kt < 16; ++kt) {
        const char* An = Ab + kt * 16384;
        const char* Bn = Bb + kt * 16384;
        #pragma unroll
        for (int i = 0; i < 4; ++i) {
            gll16(An + w * 4096 + i * 1024 + l * 16, &AsB[w * 4096 + i * 1024]);
            gll16(Bn + w * 4096 + i * 1024 + l * 16, &BsB[w * 4096 + i * 1024]);
        }
        asm volatile("s_waitcnt vmcnt(0)" ::: "memory");
        __syncthreads();
        #pragma unroll
        for (int kc = 0; kc < 2; ++kc) {
            const int key = ((kc * 4 + lg) ^ (li & 7)) << 4;
            bf16x8 a[4], b[4];
            #pragma unroll
            for (int f = 0; f < 4; ++f)
                a[f] = *(const bf16x8*)&AsB[(wm * 64 + f * 16 + li) * 128 + key];
            #pragma unroll
            for (int f = 0; f < 4; ++f)
                b[f] = *(const bf16x8*)&BsB[(wn * 64 + f * 16 + li) * 128 + key];
            #pragma unroll
            for (int mi = 0; mi < 4; ++mi)
                #pragma unroll
                for (int ni = 0; ni < 4; ++ni)
                    acc[mi][ni] = __builtin_amdgcn_mfma_f32_16x16x32_bf16(a[mi], b[ni], acc[mi][ni], 0, 0, 0);
        }
        __syncthreads();
    }

    const int mb = m0 + wm * 64;
    const int nb0 = n0 + wn * 64;
    if constexpr (EPI == 0) {
        const int part = n0 >> 10;
        if (part < 2) {
            u16* dst = (part == 0) ? q : k;
            const float scl = (part == 0) ? QSCALE : 1.0f;
            #pragma unroll
            for (int mi = 0; mi < 4; ++mi)
                #pragma unroll
                for (int r = 0; r < 4; ++r) {
                    const int m = mb + mi * 16 + lg * 4 + r;
                    const int bb = m >> 11, t = m & 2047;
                    #pragma unroll
                    for (int ni = 0; ni < 4; ++ni) {
                        const int n = nb0 + ni * 16 + li;
                        const int c = n & 1023;
                        const int h = c >> 6, d = c & 63;
                        const float val = (acc[mi][ni][r] + bias[n]) * scl;
                        dst[(((bb << 4) + h) * T_ + t) * DH + d] = f2bf(val);
                    }
                }
        } else {
            // V transposed: vt[((b*16+h)*64 + d)*2048 + t]
            #pragma unroll
            for (int mi = 0; mi < 4; ++mi) {
                const int m = mb + mi * 16 + lg * 4;
                const int bb = m >> 11, t0 = m & 2047;
                #pragma unroll
                for (int ni = 0; ni < 4; ++ni) {
                    const int n = nb0 + ni * 16 + li;
                    const int c = n & 1023;
                    const int h = c >> 6, d = c & 63;
                    const float bz = bias[n];
                    u32 w0 = pkbf(acc[mi][ni][0] + bz, acc[mi][ni][1] + bz);
                    u32 w1 = pkbf(acc[mi][ni][2] + bz, acc[mi][ni][3] + bz);
                    *(uint2*)&vt[(((bb << 4) + h) * 64 + d) * (size_t)T_ + t0] = make_uint2(w0, w1);
                }
            }
        }
    } else {
        #pragma unroll
        for (int mi = 0; mi < 4; ++mi)
            #pragma unroll
            for (int r = 0; r < 4; ++r) {
                const int m = mb + mi * 16 + lg * 4 + r;
                #pragma unroll
                for (int ni = 0; ni < 4; ++ni) {
                    const int n = nb0 + ni * 16 + li;
                    outF[m * 1024 + n] = acc[mi][ni][r] + bias[n];
                }
            }
    }
}

// ---------------- MFMA flash attention v12-LPT (R18 winner: 47.5us): swapped-QK ----------------
// 256 thr / 4 waves, Q-tile 64, KV tile 64, dbuf K/V LDS (40KB, 4 blocks/CU = grid cap),
// grid (32 bh, 32 slots) with LPT map (qt = 31 - slot): heavy blocks dispatch first,
// 1-tile blocks drain the tail. Swapped-QK (S^T) -> lane-local softmax, defer-max,
// exp2 domain, ds_write_b64 P, setprio on MFMA clusters.
__global__ __launch_bounds__(256, 2) void flash_attn(
    const u16* __restrict__ Q, const u16* __restrict__ K,
    const u16* __restrict__ Vt, char* __restrict__ Yt)
{
    __shared__ __align__(16) char KsB[2][8192];
    __shared__ __align__(16) char VsB[2][8192];
    __shared__ __align__(16) char PsB[4][2048];

    const int bh = blockIdx.x;
    const int slot = blockIdx.y;
    const int qt = 31 - slot;                     // LPT: heaviest first
    const int tid = threadIdx.x;
    const int w  = tid >> 6;
    const int l  = tid & 63;
    const int li = l & 15, lg = l >> 4;
    const u16* Qb = Q  + (size_t)bh * (T_ * DH);
    const u16* Kb = K  + (size_t)bh * (T_ * DH);
    const u16* Vb = Vt + (size_t)bh * (T_ * DH);   // rows (d) of length T_
    const int srow = tid >> 3;   // 0..31
    const int sseg = tid & 7;    // 16B segment
    char* Pw = PsB[w];
    const int b = bh >> 4, h = bh & 15;
    const int skey = (srow & 7) << 4;   // (srow+32)&7 == srow&7
    const int rdkey = (li & 7) << 4;

    const int wq0 = qt * 64 + w * 16;
    const int q_row = wq0 + li;          // this lane's q row
    const int nkv = qt + 1;

    bf16x8 qa[2];
    qa[0] = *(const bf16x8*)(Qb + q_row * 64 + 0  + lg * 8);
    qa[1] = *(const bf16x8*)(Qb + q_row * 64 + 32 + lg * 8);

    f32x4 o[4];   // o[nb][r] = O[q=li][d=nb*16+lg*4+r]
    #pragma unroll
    for (int nb = 0; nb < 4; ++nb) o[nb] = (f32x4){0.f, 0.f, 0.f, 0.f};
    float m_r = -INFINITY, l_r = 0.f;    // lane-scalar (q-row li)

    uint4 kr0, kr1, vr0, vr1;
    // ---- prologue: stage tile 0 into buf 0 (rows srow and srow+32) ----
    kr0 = *(const uint4*)(Kb + srow * 64 + sseg * 8);
    kr1 = *(const uint4*)(Kb + (srow + 32) * 64 + sseg * 8);
    vr0 = *(const uint4*)(Vb + (size_t)srow * T_ + sseg * 8);
    vr1 = *(const uint4*)(Vb + (size_t)(srow + 32) * T_ + sseg * 8);
    *(uint4*)&KsB[0][srow * 128        + ((sseg << 4) ^ skey)] = kr0;
    *(uint4*)&KsB[0][(srow + 32) * 128 + ((sseg << 4) ^ skey)] = kr1;
    *(uint4*)&VsB[0][srow * 128        + ((sseg << 4) ^ skey)] = vr0;
    *(uint4*)&VsB[0][(srow + 32) * 128 + ((sseg << 4) ^ skey)] = vr1;
    __syncthreads();

    for (int j = 0; j < nkv; ++j) {
        const int cur = j & 1;
        const bool has_next = (j + 1 < nkv);
        // ---- issue next tile's global loads (latency hides under compute) ----
        if (has_next) {
            const int t0 = (j + 1) * 64;
            kr0 = *(const uint4*)(Kb + (t0 + srow) * 64 + sseg * 8);
            kr1 = *(const uint4*)(Kb + (t0 + srow + 32) * 64 + sseg * 8);
            vr0 = *(const uint4*)(Vb + (size_t)srow * T_ + t0 + sseg * 8);
            vr1 = *(const uint4*)(Vb + (size_t)(srow + 32) * T_ + t0 + sseg * 8);
        }
        // ---- S^T = K.Q^T : s[f][r] = S[q=li][k = j*64 + f*16 + lg*4 + r] ----
        const char* Kc = KsB[cur];
        f32x4 s[4];
        __builtin_amdgcn_s_setprio(1);
        #pragma unroll
        for (int f = 0; f < 4; ++f) {
            s[f] = (f32x4){0.f, 0.f, 0.f, 0.f};
            #pragma unroll
            for (int c = 0; c < 2; ++c) {
                bf16x8 kb = *(const bf16x8*)&Kc[(f * 16 + li) * 128 + ((c * 64 + lg * 16) ^ rdkey)];
                s[f] = __builtin_amdgcn_mfma_f32_16x16x32_bf16(kb, qa[c], s[f], 0, 0, 0);
            }
        }
        __builtin_amdgcn_s_setprio(0);
        // ---- causal mask on diagonal tile (only j==qt can cross) ----
        if ((j + 1) * 64 > wq0) {
            const int kbase = j * 64 + lg * 4;
            #pragma unroll
            for (int f = 0; f < 4; ++f)
                #pragma unroll
                for (int r = 0; r < 4; ++r)
                    if (kbase + f * 16 + r > q_row) s[f][r] = -INFINITY;
        }
        // ---- softmax: lane-local max check; cross-reduce only on rescale ----
        float lm = s[0][0];
        #pragma unroll
        for (int f = 0; f < 4; ++f)
            #pragma unroll
            for (int r = 0; r < 4; ++r) lm = fmaxf(lm, s[f][r]);
        if (!__all(lm <= m_r + DEFER_THR)) {
            float tm = lm;
            tm = fmaxf(tm, __shfl_xor(tm, 16));
            tm = fmaxf(tm, __shfl_xor(tm, 32));
            const float mnew = fmaxf(m_r, tm);
            const float corr = exp2f(m_r - mnew);
            m_r = mnew;
            l_r *= corr;
            #pragma unroll
            for (int nb = 0; nb < 4; ++nb)
                #pragma unroll
                for (int r = 0; r < 4; ++r) o[nb][r] *= corr;
        }
        // ---- P = exp2(S - m), accumulate l, pack & write (4x ds_write_b64) ----
        #pragma unroll
        for (int f = 0; f < 4; ++f) {
            float p0 = exp2f(s[f][0] - m_r);
            float p1 = exp2f(s[f][1] - m_r);
            float p2 = exp2f(s[f][2] - m_r);
            float p3 = exp2f(s[f][3] - m_r);
            l_r += (p0 + p1) + (p2 + p3);
            uint2 pk = make_uint2(pkbf(p0, p1), pkbf(p2, p3));
            *(uint2*)&Pw[li * 128 + (((f * 32 + lg * 8)) ^ rdkey)] = pk;
        }
        // ---- write prefetched K/V into the other buffer ----
        if (has_next) {
            *(uint4*)&KsB[cur ^ 1][srow * 128        + ((sseg << 4) ^ skey)] = kr0;
            *(uint4*)&KsB[cur ^ 1][(srow + 32) * 128 + ((sseg << 4) ^ skey)] = kr1;
            *(uint4*)&VsB[cur ^ 1][srow * 128        + ((sseg << 4) ^ skey)] = vr0;
            *(uint4*)&VsB[cur ^ 1][(srow + 32) * 128 + ((sseg << 4) ^ skey)] = vr1;
        }
        // ---- O^T += V^T.P^T : o[nb][r] = O[q=li][d=nb*16+lg*4+r] ----
        const char* Vc = VsB[cur];
        __builtin_amdgcn_s_setprio(1);
        #pragma unroll
        for (int c = 0; c < 2; ++c) {
            bf16x8 pa = *(const bf16x8*)&Pw[li * 128 + ((c * 64 + lg * 16) ^ rdkey)];
            #pragma unroll
            for (int nb = 0; nb < 4; ++nb) {
                bf16x8 vb = *(const bf16x8*)&Vc[(nb * 16 + li) * 128 + ((c * 64 + lg * 16) ^ rdkey)];
                o[nb] = __builtin_amdgcn_mfma_f32_16x16x32_bf16(vb, pa, o[nb], 0, 0, 0);
            }
        }
        __builtin_amdgcn_s_setprio(0);
        __syncthreads();
    }

    // ---- epilogue: cross-reduce l, normalize, write Y (tiled-swizzled, 8B stores) ----
    l_r += __shfl_xor(l_r, 16);
    l_r += __shfl_xor(l_r, 32);
    const float inv = 1.0f / l_r;
    // matrix row = b*2048 + qt*64 + w*16 + li  ->  mt = b*16 + (qt>>1)
    const int r128 = (qt & 1) * 64 + w * 16 + li;
    const int rk = (r128 & 7) << 4;
    char* yrow = Yt + ((size_t)((b * 16 + (qt >> 1)) * 16 + h)) * 16384 + r128 * 128;
    #pragma unroll
    for (int nb = 0; nb < 4; ++nb) {
        // d = nb*16 + lg*4 + r, r=0..3 -> seg = 2nb + (lg>>1), byte e0 = (lg&1)*8
        const int seg = 2 * nb + (lg >> 1);
        uint2 pk = make_uint2(pkbf(o[nb][0] * inv, o[nb][1] * inv),
                              pkbf(o[nb][2] * inv, o[nb][3] * inv));
        *(uint2*)&yrow[((seg << 4) ^ rk) + (lg & 1) * 8] = pk;
    }
}

extern "C" void kernel_launch(void* const* d_in, const int* in_sizes, int n_in,
                              void* d_out, int out_size, void* d_ws, size_t ws_size,
                              hipStream_t stream) {
    const float* x      = (const float*)d_in[0];
    const float* W_attn = (const float*)d_in[1];
    const float* b_attn = (const float*)d_in[2];
    const float* W_proj = (const float*)d_in[3];
    const float* b_proj = (const float*)d_in[4];
    float* out = (float*)d_out;

    char* ws = (char*)d_ws;
    u16* q   = (u16*)ws;                          // [B,H,T,D] bf16, 8 MB
    u16* k   = (u16*)(ws + (8u << 20));           // [B,H,T,D] 8 MB
    u16* vt  = (u16*)(ws + (16u << 20));          // [B,H,D,T] 8 MB
    char* xb = ws + (24u << 20);                  // x tiled bf16 8 MB; REUSED as Yt after qkv
    char* wab = ws + (32u << 20);                 // W_attn tiled bf16 6 MB
    char* wpb = ws + (38u << 20);                 // W_proj tiled bf16 2 MB

    cvt_all<<<4096, 256, 0, stream>>>(x, W_attn, W_proj, (u16*)xb, (u16*)wab, (u16*)wpb);
    gemm_lds<0><<<dim3(24, 32), 256, 0, stream>>>(xb, wab, b_attn, q, k, vt, nullptr);
    flash_attn<<<dim3(32, 32), 256, 0, stream>>>(q, k, vt, xb /* Yt */);
    gemm_lds<1><<<dim3(8, 32), 256, 0, stream>>>(xb /* Yt */, wpb, b_proj,
                                                 nullptr, nullptr, nullptr, out);
}